// Round 2
// baseline (10256.692 us; speedup 1.0000x reference)
//
#include <hip/hip_runtime.h>
#include <math.h>

#define NV 50000
#define NB 2048
#define NKEEP 65          // K+1
#define RADIUS_F 0.2f

#define FPS_NBLK 32
#define FPS_NTHR 1024

#define ROW_THR 256
#define CAP 5376          // candidate buffer per row (LDS)

// ---------------- no-contract arithmetic helpers ----------------
// (#pragma clang fp contract(off) must open a compound statement; function
//  bodies are the guaranteed-legal placement)

static __device__ __forceinline__ float sn_nc(float x, float y, float z) {
#pragma clang fp contract(off)
  return (x * x + y * y) + z * z;
}

static __device__ __forceinline__ float d2_nc(float ax, float ay, float az,
                                              float bx, float by, float bz) {
#pragma clang fp contract(off)
  float dx = ax - bx, dy = ay - by, dz = az - bz;
  return (dx * dx + dy * dy) + dz * dz;
}

static __device__ __forceinline__ float tval_nc(float cx, float cy, float cz,
                                                float px, float py, float pz,
                                                float pw) {
#pragma clang fp contract(off)
  float gd = (cx * px + cy * py) + cz * pz;
  return (pw - 2.0f * gd) + pw;
}

// ---------------- helpers ----------------

static __device__ __forceinline__ unsigned long long pack_key(float v, unsigned idx) {
  // v >= 0 so float bits are monotone; ties -> smaller idx wins (matches jnp.argmax / top_k)
  return ((unsigned long long)__float_as_uint(v) << 32) | (0xFFFFFFFFu - idx);
}

static __device__ __forceinline__ unsigned long long wave_max(unsigned long long k) {
#pragma unroll
  for (int m = 1; m < 64; m <<= 1) {
    unsigned long long o = __shfl_xor(k, m, 64);
    if (o > k) k = o;
  }
  return k;
}

static __device__ __forceinline__ void gbar(unsigned* bar) {
  __syncthreads();
  if (threadIdx.x == 0) {
    unsigned g = __hip_atomic_load(&bar[1], __ATOMIC_RELAXED, __HIP_MEMORY_SCOPE_AGENT);
    unsigned a = __hip_atomic_fetch_add(&bar[0], 1u, __ATOMIC_ACQ_REL, __HIP_MEMORY_SCOPE_AGENT);
    if (a == FPS_NBLK - 1) {
      __hip_atomic_store(&bar[0], 0u, __ATOMIC_RELAXED, __HIP_MEMORY_SCOPE_AGENT);
      __hip_atomic_fetch_add(&bar[1], 1u, __ATOMIC_ACQ_REL, __HIP_MEMORY_SCOPE_AGENT);
    } else {
      unsigned cur;
      do {
        __builtin_amdgcn_s_sleep(1);
        cur = __hip_atomic_load(&bar[1], __ATOMIC_ACQUIRE, __HIP_MEMORY_SCOPE_AGENT);
      } while (cur == g);
    }
  }
  __syncthreads();
}

// ---------------- kernel 0: pack (x,y,z,sn) + init control state ----------------

__global__ void k_init(const float* __restrict__ vtx, float4* __restrict__ pts,
                       int* __restrict__ cidx, unsigned* __restrict__ bar) {
  int i = blockIdx.x * blockDim.x + threadIdx.x;
  if (i < NV) {
    float x = vtx[3 * i], y = vtx[3 * i + 1], z = vtx[3 * i + 2];
    pts[i] = make_float4(x, y, z, sn_nc(x, y, z));
  }
  if (i == 0) { cidx[0] = 0; bar[0] = 0u; bar[1] = 0u; }
}

// ---------------- kernel 1: FPS (cooperative, registers-resident) ----------------

__global__ __launch_bounds__(FPS_NTHR, 1)
void k_fps(const float4* __restrict__ pts, int* __restrict__ cidx,
           unsigned long long* __restrict__ bmax, unsigned* __restrict__ bar) {
  const int tid = threadIdx.x;
  const int bid = blockIdx.x;
  const int g0 = bid * FPS_NTHR + tid;
  const int g1 = g0 + FPS_NBLK * FPS_NTHR;

  float x0 = 0.f, y0 = 0.f, z0 = 0.f, x1 = 0.f, y1 = 0.f, z1 = 0.f;
  const bool l0 = g0 < NV, l1 = g1 < NV;
  if (l0) { float4 p = pts[g0]; x0 = p.x; y0 = p.y; z0 = p.z; }
  if (l1) { float4 p = pts[g1]; x1 = p.x; y1 = p.y; z1 = p.z; }

  float m0 = 0.f, m1 = 0.f;
  {
    float4 s = pts[0];
    if (l0) m0 = d2_nc(x0, y0, z0, s.x, s.y, s.z);
    if (l1) m1 = d2_nc(x1, y1, z1, s.x, s.y, s.z);
  }

  __shared__ unsigned long long s_w[16];
  __shared__ int s_win;

  auto block_store_max = [&](int par) {
    unsigned long long k = l0 ? pack_key(m0, (unsigned)g0) : 0ull;
    if (l1) { unsigned long long k1 = pack_key(m1, (unsigned)g1); if (k1 > k) k = k1; }
    k = wave_max(k);
    if ((tid & 63) == 0) s_w[tid >> 6] = k;
    __syncthreads();
    if (tid < 64) {
      unsigned long long kk = (tid < 16) ? s_w[tid] : 0ull;
      kk = wave_max(kk);
      if (tid == 0)
        __hip_atomic_store(&bmax[par * FPS_NBLK + bid], kk, __ATOMIC_RELAXED,
                           __HIP_MEMORY_SCOPE_AGENT);
    }
  };

  block_store_max(0);
  gbar(bar);

  for (int t = 1; t < NB; ++t) {
    const int rpar = (t - 1) & 1;
    const int wpar = t & 1;

    if (tid < 64) {
      unsigned long long kk = 0ull;
      if (tid < FPS_NBLK)
        kk = __hip_atomic_load(&bmax[rpar * FPS_NBLK + tid], __ATOMIC_RELAXED,
                               __HIP_MEMORY_SCOPE_AGENT);
      kk = wave_max(kk);
      if (tid == 0) s_win = (int)(0xFFFFFFFFu - (unsigned)(kk & 0xFFFFFFFFull));
    }
    __syncthreads();
    const int w = s_win;
    if (bid == 0 && tid == 0) cidx[t] = w;

    const float4 wp = pts[w];
    if (l0) m0 = fminf(m0, d2_nc(x0, y0, z0, wp.x, wp.y, wp.z));
    if (l1) m1 = fminf(m1, d2_nc(x1, y1, z1, wp.x, wp.y, wp.z));

    block_store_max(wpar);
    gbar(bar);
  }
}

// ---------------- kernel 2: per-centroid select + MLP + aggregate + global ----------------

__global__ __launch_bounds__(ROW_THR, 3)
void k_row(const float4* __restrict__ pts, const int* __restrict__ cidx,
           const float* __restrict__ W1, const float* __restrict__ b1,
           const float* __restrict__ W2, const float* __restrict__ b2,
           const float* __restrict__ Wg, const float* __restrict__ bg,
           float* __restrict__ out) {
  const int tid = threadIdx.x;
  const int row = blockIdx.x;

  __shared__ unsigned hist[1024];
  __shared__ unsigned psum[ROW_THR];
  __shared__ float cd[CAP];
  __shared__ int cidb[CAP];
  __shared__ int vlist[NKEEP];
  __shared__ float s_h[4][64];
  __shared__ float s_mred[4][64];
  __shared__ float s_agg[64];
  __shared__ int s_validn, s_k, s_mode, s_ncand, s_cntle;

  const float4 c4 = pts[cidx[row]];

  for (int i = tid; i < 1024; i += ROW_THR) hist[i] = 0u;
  if (tid == 0) { s_ncand = 0; s_cntle = 0; }
  __syncthreads();

  // pass 1: histogram of d over [0, 0.2]
  for (int j = tid; j < NV; j += ROW_THR) {
    const float4 p = pts[j];
    const float t = tval_nc(c4.x, c4.y, c4.z, p.x, p.y, p.z, p.w);
    const float at = fabsf(t);
    if (at <= 0.0402f) {                 // conservative prefilter: d > 0.2004 otherwise
      const float d = sqrtf(at);
      if (d <= RADIUS_F) {
        atomicAdd(&s_cntle, 1);
        int b = (int)(d * 5120.0f); if (b > 1023) b = 1023;
        atomicAdd(&hist[b], 1u);
      }
    }
  }
  __syncthreads();

  {
    const int base = tid * 4;
    psum[tid] = hist[base] + hist[base + 1] + hist[base + 2] + hist[base + 3];
  }
  __syncthreads();
  if (tid == 0) {
    if (s_cntle <= NKEEP) {
      s_mode = 0; s_k = 1023;            // all in-radius points are valid
    } else {
      int cum = 0, kk = 1023;
      for (int i = 0; i < ROW_THR; ++i) {
        const int nc = cum + (int)psum[i];
        if (nc >= NKEEP) {
          int c2 = cum;
          for (int b = 0; b < 4; ++b) {
            c2 += (int)hist[i * 4 + b];
            if (c2 >= NKEEP) { kk = i * 4 + b; break; }
          }
          break;
        }
        cum = nc;
      }
      s_mode = 1; s_k = kk;
    }
  }
  __syncthreads();
  const int mode = s_mode, kbin = s_k;

  // pass 2: compact candidates
  for (int j = tid; j < NV; j += ROW_THR) {
    const float4 p = pts[j];
    const float t = tval_nc(c4.x, c4.y, c4.z, p.x, p.y, p.z, p.w);
    const float at = fabsf(t);
    if (at <= 0.0402f) {
      const float d = sqrtf(at);
      if (d <= RADIUS_F) {
        int b = (int)(d * 5120.0f); if (b > 1023) b = 1023;
        if (mode == 0 || b <= kbin) {
          const int pos = atomicAdd(&s_ncand, 1);
          if (pos < CAP) { cd[pos] = d; cidb[pos] = j; }
        }
      }
    }
  }
  __syncthreads();
  int n = s_ncand; if (n > CAP) n = CAP;

  if (mode == 0) {
    if (tid < n) vlist[tid] = cidb[tid];       // n <= 65, all valid (max-agg is order-free)
    if (tid == 0) s_validn = n;
  } else {
    // exact 65 smallest by (d, idx) lexicographic (matches lax.top_k tie-break)
    for (int c = tid; c < n; c += ROW_THR) {
      const float dc = cd[c]; const int ic = cidb[c];
      int r = 0;
      for (int j2 = 0; j2 < n; ++j2) {
        const float dj = cd[j2]; const int ij = cidb[j2];
        r += (int)((dj < dc) | ((dj == dc) & (ij < ic)));
      }
      if (r < NKEEP) vlist[r] = ic;
    }
    if (tid == 0) s_validn = NKEEP;
  }
  __syncthreads();
  const int nvld = s_validn;

  // MLP: 4 neighbor-groups x 64 channels
  const int ch = tid & 63, grp = tid >> 6;
  float amax = -INFINITY;
  for (int base = 0; base < nvld; base += 4) {
    const int slot = base + grp;
    if (slot < nvld) {
      const int j = vlist[slot];
      const float4 p = pts[j];
      const float f3 = p.x - c4.x, f4 = p.y - c4.y, f5 = p.z - c4.z;
      float hs = p.x * W1[ch] + p.y * W1[64 + ch] + p.z * W1[128 + ch]
               + f3 * W1[192 + ch] + f4 * W1[256 + ch] + f5 * W1[320 + ch];
      hs += b1[ch];
      s_h[grp][ch] = fmaxf(hs, 0.f);
    }
    __syncthreads();
    if (slot < nvld) {
      float acc = 0.f;
#pragma unroll 8
      for (int k2 = 0; k2 < 64; ++k2) acc += s_h[grp][k2] * W2[k2 * 64 + ch];
      acc += b2[ch];
      amax = fmaxf(amax, acc);
    }
    __syncthreads();
  }
  s_mred[grp][ch] = amax;
  __syncthreads();
  if (tid < 64) {
    s_agg[tid] = fmaxf(fmaxf(s_mred[0][tid], s_mred[1][tid]),
                       fmaxf(s_mred[2][tid], s_mred[3][tid]));
  }
  __syncthreads();
  if (tid < 128) {
    float acc = 0.f;
#pragma unroll 8
    for (int k2 = 0; k2 < 64; ++k2) acc += s_agg[k2] * Wg[k2 * 128 + tid];
    out[row * 128 + tid] = acc + bg[tid];
  }
}

// ---------------- launch ----------------

extern "C" void kernel_launch(void* const* d_in, const int* in_sizes, int n_in,
                              void* d_out, int out_size, void* d_ws, size_t ws_size,
                              hipStream_t stream) {
  const float* vtx = (const float*)d_in[0];
  const float* W1  = (const float*)d_in[1];
  const float* b1  = (const float*)d_in[2];
  const float* W2  = (const float*)d_in[3];
  const float* b2  = (const float*)d_in[4];
  const float* Wg  = (const float*)d_in[5];
  const float* bg  = (const float*)d_in[6];
  float* out = (float*)d_out;

  char* ws = (char*)d_ws;
  float4* pts = (float4*)ws;                                        // 800000 B
  int* cidx = (int*)(ws + 800000);                                  // 8192 B
  unsigned long long* bmax = (unsigned long long*)(ws + 808192);    // 2*32*8 = 512 B
  unsigned* bar = (unsigned*)(ws + 808704);                         // 8 B

  k_init<<<dim3((NV + 255) / 256), dim3(256), 0, stream>>>(vtx, pts, cidx, bar);

  void* args[] = { (void*)&pts, (void*)&cidx, (void*)&bmax, (void*)&bar };
  (void)hipLaunchCooperativeKernel((void*)k_fps, dim3(FPS_NBLK), dim3(FPS_NTHR), args, 0, stream);

  k_row<<<dim3(NB), dim3(ROW_THR), 0, stream>>>(pts, cidx, W1, b1, W2, b2, Wg, bg, out);
}